// Round 5
// baseline (11079.041 us; speedup 1.0000x reference)
//
#include <hip/hip_runtime.h>
#include <stdint.h>

typedef unsigned short ushort_t;
typedef __bf16 bf16x8 __attribute__((ext_vector_type(8)));
typedef float f32x4 __attribute__((ext_vector_type(4)));

// ---------- bf16 <-> f32 (bit ops) ----------
__device__ __forceinline__ float b2f(ushort_t u) {
  union { unsigned u; float f; } v; v.u = ((unsigned)u) << 16; return v.f;
}
__device__ __forceinline__ ushort_t f2b(float f) {
  union { float f; unsigned u; } v; v.f = f;
  unsigned r = (v.u + 0x7FFFu + ((v.u >> 16) & 1u)) >> 16;
  return (ushort_t)r;
}

// ---------- fast transcendentals (HW v_exp_f32 based) ----------
__device__ __forceinline__ float sigm(float x)     { return 1.f / (1.f + __expf(-x)); }
__device__ __forceinline__ float tanhfast(float x) { return 1.f - 2.f / (1.f + __expf(2.f * x)); }

// ---------- global -> LDS direct load, 16B per lane ----------
__device__ __forceinline__ void gload_lds16(const void* g, void* lds) {
  auto l3 = reinterpret_cast<__attribute__((address_space(3))) unsigned*>(
      reinterpret_cast<uintptr_t>(lds));
  __builtin_amdgcn_global_load_lds(reinterpret_cast<const unsigned*>(g), l3, 16, 0, 0);
}

// ---------- device-scope grid barrier (blocks must be co-resident) ----------
__device__ __forceinline__ void grid_barrier(unsigned* bar, unsigned target) {
  __threadfence();          // release this thread's writes device-wide
  __syncthreads();          // all threads of block released before arrive
  if (threadIdx.x == 0) {
    __hip_atomic_fetch_add(bar, 1u, __ATOMIC_RELEASE, __HIP_MEMORY_SCOPE_AGENT);
    while (__hip_atomic_load(bar, __ATOMIC_ACQUIRE, __HIP_MEMORY_SCOPE_AGENT) < target)
      __builtin_amdgcn_s_sleep(4);
  }
  __syncthreads();
  __threadfence();          // acquire: invalidate stale cached lines
}

// =====================================================================
// GEMM: C[M,N] = A[M,K] @ B[N,K]^T + bias0 + bias1 (bf16 in, f32 acc,
// bf16 or f32 out). BM=BN=128, BK=32, 256 thr (4 waves), global_load_lds
// staging (m97 structure) + bijective XCD swizzle when nwg%8==0.
// Requires: M%128==0, Kpad%32==0, lda/ldb%8==0, B zero-padded to gridDim.y*128 rows.
// =====================================================================
template <bool F32OUT>
__global__ __launch_bounds__(256) void gemm_bt(
    const ushort_t* __restrict__ A, const ushort_t* __restrict__ B,
    void* __restrict__ Cv,
    const float* __restrict__ bias0, const float* __restrict__ bias1,
    int lda, int ldb, int ldc, int Kpad, int N)
{
  __shared__ alignas(16) ushort_t As[128 * 32];
  __shared__ alignas(16) ushort_t Bs[128 * 32];
  const int tid = threadIdx.x;
  const int w = tid >> 6, l = tid & 63;
  const int wr = w >> 1, wc = w & 1;

  // XCD-aware bijective swizzle (valid when nwg % 8 == 0)
  unsigned nwg = gridDim.x * gridDim.y;
  unsigned wg = blockIdx.y * gridDim.x + blockIdx.x;
  if ((nwg & 7u) == 0u) {
    unsigned cpx = nwg >> 3;
    wg = (wg & 7u) * cpx + (wg >> 3);
  }
  const long m0 = (long)(wg % gridDim.x) * 128;
  const long n0 = (long)(wg / gridDim.x) * 128;

  const int lrow = l & 15, lk = (l >> 4) * 8;

  f32x4 acc[4][4] = {};

  const int c0 = tid, c1 = tid + 256;       // 16B chunks of the 128x32 tile
  const int r0 = c0 >> 2, g0 = (c0 & 3) * 8;
  const int r1 = c1 >> 2, g1 = (c1 & 3) * 8;

  for (int k0 = 0; k0 < Kpad; k0 += 32) {
    gload_lds16(A + (m0 + r0) * lda + k0 + g0, As + c0 * 8);
    gload_lds16(A + (m0 + r1) * lda + k0 + g1, As + c1 * 8);
    gload_lds16(B + (n0 + r0) * ldb + k0 + g0, Bs + c0 * 8);
    gload_lds16(B + (n0 + r1) * ldb + k0 + g1, Bs + c1 * 8);
    __syncthreads();

    bf16x8 af[4], bfr[4];
#pragma unroll
    for (int mi = 0; mi < 4; mi++)
      af[mi] = *(const bf16x8*)(As + (wr * 64 + mi * 16 + lrow) * 32 + lk);
#pragma unroll
    for (int ni = 0; ni < 4; ni++)
      bfr[ni] = *(const bf16x8*)(Bs + (wc * 64 + ni * 16 + lrow) * 32 + lk);
#pragma unroll
    for (int mi = 0; mi < 4; mi++)
#pragma unroll
      for (int ni = 0; ni < 4; ni++)
        acc[mi][ni] = __builtin_amdgcn_mfma_f32_16x16x32_bf16(af[mi], bfr[ni], acc[mi][ni], 0, 0, 0);
    __syncthreads();
  }

  // epilogue: D layout col=lane&15, row=(lane>>4)*4+reg
  const int rbase = (l >> 4) * 4;
#pragma unroll
  for (int ni = 0; ni < 4; ni++) {
    int gcol = (int)n0 + wc * 64 + ni * 16 + lrow;
    if (gcol < N) {
      float badd = 0.f;
      if (bias0) badd += bias0[gcol];
      if (bias1) badd += bias1[gcol];
#pragma unroll
      for (int mi = 0; mi < 4; mi++) {
#pragma unroll
        for (int r = 0; r < 4; r++) {
          long grow = m0 + wr * 64 + mi * 16 + rbase + r;
          float v = acc[mi][ni][r] + badd;
          if (F32OUT) ((float*)Cv)[grow * ldc + gcol] = v;
          else        ((ushort_t*)Cv)[grow * ldc + gcol] = f2b(v);
        }
      }
    }
  }
}

// =====================================================================
// Persistent LSTM layer: 100 time steps in ONE kernel. Grid = 72 blocks
// (one per 16-unit slice) x 256 thr (4 waves = 4 batch-16 tiles). Each wave
// computes all 4 gates for its batch tile -> cell update is lane-local
// (no LDS, no __syncthreads). One device grid barrier per step.
// =====================================================================
__global__ __launch_bounds__(256) void lstm_layer(
    ushort_t* __restrict__ hs,        // [101][64][1152] bf16
    const ushort_t* __restrict__ G,   // [6400][4608] bf16 (x@Wih^T + biases)
    const ushort_t* __restrict__ Whh, // padded [4608][1152] bf16
    float* __restrict__ c_ws,         // [64][1150] f32
    unsigned* __restrict__ bar)
{
  const int tid = threadIdx.x;
  const int w = tid >> 6, l = tid & 63;   // wave w = batch tile w (rows w*16..+16)
  const int us = blockIdx.x;              // unit slice [0,72)
  const int lrow = l & 15, lk = (l >> 4) * 8;
  const int u = us * 16 + lrow;           // output unit of this lane (D col = l&15)
  const int row0 = w * 16 + (l >> 4) * 4; // first batch row of this lane's D regs

  // loop-invariant Whh fragment pointers (one per gate; rows g*1150+us*16+lrow)
  const ushort_t* B0 = Whh + ((long)(0 * 1150 + us * 16 + lrow)) * 1152 + lk;
  const ushort_t* B1 = Whh + ((long)(1 * 1150 + us * 16 + lrow)) * 1152 + lk;
  const ushort_t* B2 = Whh + ((long)(2 * 1150 + us * 16 + lrow)) * 1152 + lk;
  const ushort_t* B3 = Whh + ((long)(3 * 1150 + us * 16 + lrow)) * 1152 + lk;

  for (int t = 0; t < 100; ++t) {
    const ushort_t* hp = hs + (long)t * 73728 + (long)(w * 16 + lrow) * 1152 + lk;
    f32x4 a0 = {}, a1 = {}, a2 = {}, a3 = {};
#pragma unroll
    for (int kc = 0; kc < 36; ++kc) {
      bf16x8 a = *(const bf16x8*)(hp + kc * 32);
      a0 = __builtin_amdgcn_mfma_f32_16x16x32_bf16(a, *(const bf16x8*)(B0 + kc * 32), a0, 0, 0, 0);
      a1 = __builtin_amdgcn_mfma_f32_16x16x32_bf16(a, *(const bf16x8*)(B1 + kc * 32), a1, 0, 0, 0);
      a2 = __builtin_amdgcn_mfma_f32_16x16x32_bf16(a, *(const bf16x8*)(B2 + kc * 32), a2, 0, 0, 0);
      a3 = __builtin_amdgcn_mfma_f32_16x16x32_bf16(a, *(const bf16x8*)(B3 + kc * 32), a3, 0, 0, 0);
    }

    if (u < 1150) {
#pragma unroll
      for (int r = 0; r < 4; ++r) {
        int b = row0 + r;
        long grow = ((long)t * 64 + b) * 4608;
        float iv = a0[r] + b2f(G[grow + u]);
        float fv = a1[r] + b2f(G[grow + 1150 + u]);
        float gv = a2[r] + b2f(G[grow + 2300 + u]);
        float ov = a3[r] + b2f(G[grow + 3450 + u]);
        float c_old = c_ws[b * 1150 + u];
        float cn = sigm(fv) * c_old + sigm(iv) * tanhfast(gv);
        float hv = sigm(ov) * tanhfast(cn);
        c_ws[b * 1150 + u] = cn;
        hs[(long)(t + 1) * 73728 + (long)b * 1152 + u] = f2b(hv);
      }
    }
    grid_barrier(bar, (unsigned)(t + 1) * 72u);
  }
}

// =====================================================================
// Fused causal attention for one (t,b): scores -> softmax -> PV. f32 math.
// =====================================================================
__global__ __launch_bounds__(256) void attn_kernel(
    const ushort_t* __restrict__ hs2,  // base at hs[1]: [100][64][1152] bf16
    ushort_t* __restrict__ outp)       // [6400][1152] bf16
{
  __shared__ float qf[1152];
  __shared__ float sc[104];
  __shared__ float sinv;
  const int rowi = blockIdx.x;  // t*64 + b
  const int t = rowi >> 6, b = rowi & 63;
  const int tid = threadIdx.x;
  const int w = tid >> 6, l = tid & 63;

  const ushort_t* q = hs2 + (long)rowi * 1152;
  for (int c = tid; c < 1150; c += 256) qf[c] = b2f(q[c]);
  __syncthreads();

  for (int s = w; s <= t; s += 4) {
    const ushort_t* k = hs2 + (long)(s * 64 + b) * 1152;
    float p = 0.f;
    for (int h = l; h < 1150; h += 64) p += qf[h] * b2f(k[h]);
    for (int off = 32; off; off >>= 1) p += __shfl_down(p, off);
    if (l == 0) sc[s] = p;
  }
  __syncthreads();

  if (w == 0) {
    float m = -1e30f;
    for (int s = l; s <= t; s += 64) m = fmaxf(m, sc[s]);
    for (int off = 32; off; off >>= 1) m = fmaxf(m, __shfl_down(m, off));
    m = __shfl(m, 0);
    float sum = 0.f;
    for (int s = l; s <= t; s += 64) { float e = __expf(sc[s] - m); sc[s] = e; sum += e; }
    for (int off = 32; off; off >>= 1) sum += __shfl_down(sum, off);
    if (l == 0) sinv = 1.f / sum;
  }
  __syncthreads();

  const float si = sinv;
  for (int h = tid; h < 1150; h += 256) {
    float a = 0.f;
    for (int s = 0; s <= t; s++) a += sc[s] * b2f(hs2[(long)(s * 64 + b) * 1152 + h]);
    outp[(long)rowi * 1152 + h] = f2b(a * si);
  }
  if (tid < 2) outp[(long)rowi * 1152 + 1150 + tid] = 0;  // zero K-pad for decoder
}

// ---------- f32 -> bf16 conversion helpers ----------
__global__ void embed_kernel(const int* __restrict__ in1, const int* __restrict__ in2,
                             const float* __restrict__ emb, ushort_t* __restrict__ x0)
{
  int rowi = blockIdx.x;  // t*64+b
  int l = threadIdx.x;    // 64 threads
  long r1 = (long)in1[rowi] * 400, r2 = (long)in2[rowi] * 400;
  ushort_t* d = x0 + (long)rowi * 800;
  for (int c = l; c < 800; c += 64)
    d[c] = f2b(c < 400 ? emb[r1 + c] : emb[r2 + c - 400]);
}

__global__ void pad_convert(const float* __restrict__ in, ushort_t* __restrict__ out,
                            int R, int Cin, int total, int Cp)
{
  int idx = blockIdx.x * 256 + threadIdx.x;
  if (idx >= total) return;
  int r = idx / Cp, c = idx - r * Cp;
  float v = (r < R && c < Cin) ? in[(long)r * Cin + c] : 0.f;
  out[idx] = f2b(v);
}

__global__ void init_state(const float* __restrict__ h_in, const float* __restrict__ c_in,
                           ushort_t* __restrict__ hs, float* __restrict__ c_ws,
                           unsigned* __restrict__ bar)
{
  int idx = blockIdx.x * 256 + threadIdx.x;  // grid covers 64*1152 = 73728
  if (idx == 0) *bar = 0u;                   // reset grid barrier for this layer
  if (idx < 64 * 1152) {
    int b = idx / 1152, c = idx - b * 1152;
    hs[idx] = (c < 1150) ? f2b(h_in[b * 1150 + c]) : (ushort_t)0;
  }
  if (idx < 64 * 1150) c_ws[idx] = c_in[idx];
  if (idx < 100 * 128) {  // zero K-pad cols of hs rows 1..100
    int t = idx >> 7, r = idx & 127, b = r >> 1, k = r & 1;
    hs[(long)(t + 1) * 73728 + b * 1152 + 1150 + k] = 0;
  }
}

// =====================================================================
extern "C" void kernel_launch(void* const* d_in, const int* in_sizes, int n_in,
                              void* d_out, int out_size, void* d_ws, size_t ws_size,
                              hipStream_t stream) {
  (void)in_sizes; (void)n_in; (void)out_size; (void)ws_size;
  const int* input  = (const int*)d_in[0];
  const int* input2 = (const int*)d_in[1];
  const float* h_in[3] = {(const float*)d_in[2], (const float*)d_in[4], (const float*)d_in[6]};
  const float* c_in[3] = {(const float*)d_in[3], (const float*)d_in[5], (const float*)d_in[7]};
  const float* emb_W = (const float*)d_in[8];
  const float* W_ih[3] = {(const float*)d_in[9],  (const float*)d_in[13], (const float*)d_in[17]};
  const float* W_hh[3] = {(const float*)d_in[10], (const float*)d_in[14], (const float*)d_in[18]};
  const float* b_ih[3] = {(const float*)d_in[11], (const float*)d_in[15], (const float*)d_in[19]};
  const float* b_hh[3] = {(const float*)d_in[12], (const float*)d_in[16], (const float*)d_in[20]};
  const float* dec_W = (const float*)d_in[21];
  const float* dec_b = (const float*)d_in[22];
  float* out = (float*)d_out;

  // ---- workspace: buffers alive during the final decoder GEMM + barrier ----
  char* base = (char*)d_ws;
  size_t off = 0;
  auto walloc = [&](size_t bytes) { char* r = base + off; off += (bytes + 255) & ~(size_t)255; return r; };
  ushort_t* decWp = (ushort_t*)walloc(33280ull * 1152 * 2);   // 76,677,120
  ushort_t* attnB = (ushort_t*)walloc(6400ull * 1152 * 2);    // 14,745,600
  float*    c_ws  = (float*)walloc(64ull * 1150 * 4);         //    294,400
  unsigned* bar   = (unsigned*)walloc(256);

  // ---- layer-phase scratch inside d_out (852 MB f32; scratch uses first
  //      ~120 MB, all dead before the decoder GEMM which reads only ws and
  //      rewrites every element of d_out). ----
  char* ob = (char*)d_out;
  ushort_t* G   = (ushort_t*)(ob + 0);            // 6400*4608*2 = 58,982,400
  ushort_t* x0  = (ushort_t*)(ob + 58982400);     // 6400*800*2  = 10,240,000
  ushort_t* Wp  = (ushort_t*)(ob + 69222400);     // 4608*1152*2 = 10,616,832
  ushort_t* Whp = (ushort_t*)(ob + 79839232);     // 4608*1152*2 = 10,616,832
  ushort_t* hsA = (ushort_t*)(ob + 90456064);     // 101*64*1152*2 = 14,893,056
  ushort_t* hsB = (ushort_t*)(ob + 105349120);    // -> end 120,242,176

  // ---- embedding (f32 gather -> bf16) ----
  embed_kernel<<<6400, 64, 0, stream>>>(input, input2, emb_W, x0);

  // ---- 3 LSTM layers (hs ping-pong: L0->hsA, L1: hsA->hsB, L2: hsB->hsA) ----
  ushort_t* hcur[3] = {hsA, hsB, hsA};
  const ushort_t* X = x0;
  int lda = 800, Kp = 800;
  for (int lyr = 0; lyr < 3; lyr++) {
    if (lyr == 0) {
      int tot = 4608 * 800;
      pad_convert<<<(tot + 255) / 256, 256, 0, stream>>>(W_ih[0], Wp, 4600, 800, tot, 800);
    } else {
      int tot = 4608 * 1152;
      pad_convert<<<(tot + 255) / 256, 256, 0, stream>>>(W_ih[lyr], Wp, 4600, 1150, tot, 1152);
    }
    {
      int tot = 4608 * 1152;
      pad_convert<<<(tot + 255) / 256, 256, 0, stream>>>(W_hh[lyr], Whp, 4600, 1150, tot, 1152);
    }
    gemm_bt<false><<<dim3(50, 36), 256, 0, stream>>>(X, Wp, (void*)G, b_ih[lyr], b_hh[lyr],
                                                     lda, Kp, 4608, Kp, 4600);
    init_state<<<288, 256, 0, stream>>>(h_in[lyr], c_in[lyr], hcur[lyr], c_ws, bar);
    lstm_layer<<<72, 256, 0, stream>>>(hcur[lyr], G, Whp, c_ws, bar);
    X = hcur[lyr] + 73728;  // hs[1..100] as next layer's input
    lda = 1152; Kp = 1152;
  }

  // ---- causal attention on layer-2 hidden states (hsA) -> attnB (ws) ----
  attn_kernel<<<6400, 256, 0, stream>>>(hsA + 73728, attnB);

  // ---- pad+convert decoder weight into ws ----
  {
    int tot = 33280 * 1152;
    pad_convert<<<(tot + 255) / 256, 256, 0, stream>>>(dec_W, decWp, 33278, 1150, tot, 1152);
  }

  // ---- decoder GEMM -> d_out (f32 out; reads only ws; overwrites all scratch) ----
  gemm_bt<true><<<dim3(50, 260), 256, 0, stream>>>(attnB, decWp, (void*)out, dec_b, nullptr,
                                                   1152, 1152, 33278, 1152, 33278);
}

// Round 6
// 5996.515 us; speedup vs baseline: 1.8476x; 1.8476x over previous
//
#include <hip/hip_runtime.h>
#include <stdint.h>

typedef unsigned short ushort_t;
typedef __bf16 bf16x8 __attribute__((ext_vector_type(8)));
typedef float f32x4 __attribute__((ext_vector_type(4)));

// ---------- bf16 <-> f32 (bit ops) ----------
__device__ __forceinline__ float b2f(ushort_t u) {
  union { unsigned u; float f; } v; v.u = ((unsigned)u) << 16; return v.f;
}
__device__ __forceinline__ ushort_t f2b(float f) {
  union { float f; unsigned u; } v; v.f = f;
  unsigned r = (v.u + 0x7FFFu + ((v.u >> 16) & 1u)) >> 16;
  return (ushort_t)r;
}

// ---------- fast transcendentals (HW v_exp_f32 based) ----------
__device__ __forceinline__ float sigm(float x)     { return 1.f / (1.f + __expf(-x)); }
__device__ __forceinline__ float tanhfast(float x) { return 1.f - 2.f / (1.f + __expf(2.f * x)); }

// ---------- global -> LDS direct load, 16B per lane ----------
__device__ __forceinline__ void gload_lds16(const void* g, void* lds) {
  auto l3 = reinterpret_cast<__attribute__((address_space(3))) unsigned*>(
      reinterpret_cast<uintptr_t>(lds));
  __builtin_amdgcn_global_load_lds(reinterpret_cast<const unsigned*>(g), l3, 16, 0, 0);
}

// ---------- weak grid barrier: release-writeback on arrival, RELAXED polling.
// No acquire-invalidate: consumers only read addresses produced fresh this step
// (hs[t+1]) which are never stale-cached; writer wbl2 (from the release fence)
// publishes them to the L3 coherence point. Whh/G stay L2-resident. ----------
__device__ __forceinline__ void grid_barrier_weak(unsigned* bar, unsigned target) {
  __syncthreads();                 // all lanes of block done with this step's work
  if (threadIdx.x == 0) {
    __builtin_amdgcn_fence(__ATOMIC_RELEASE, "agent");   // wbl2: publish h-writes
    __hip_atomic_fetch_add(bar, 1u, __ATOMIC_RELAXED, __HIP_MEMORY_SCOPE_AGENT);
    while (__hip_atomic_load(bar, __ATOMIC_RELAXED, __HIP_MEMORY_SCOPE_AGENT) < target)
      __builtin_amdgcn_s_sleep(2);
  }
  __syncthreads();                 // compiler + exec barrier for the block
}

// =====================================================================
// GEMM: C[M,N] = A[M,K] @ B[N,K]^T + bias0 + bias1 (bf16 in, f32 acc,
// bf16 or f32 out). BM=BN=128, BK=32, 256 thr (4 waves), global_load_lds
// staging + bijective XCD swizzle when nwg%8==0.
// =====================================================================
template <bool F32OUT>
__global__ __launch_bounds__(256) void gemm_bt(
    const ushort_t* __restrict__ A, const ushort_t* __restrict__ B,
    void* __restrict__ Cv,
    const float* __restrict__ bias0, const float* __restrict__ bias1,
    int lda, int ldb, int ldc, int Kpad, int N)
{
  __shared__ alignas(16) ushort_t As[128 * 32];
  __shared__ alignas(16) ushort_t Bs[128 * 32];
  const int tid = threadIdx.x;
  const int w = tid >> 6, l = tid & 63;
  const int wr = w >> 1, wc = w & 1;

  unsigned nwg = gridDim.x * gridDim.y;
  unsigned wg = blockIdx.y * gridDim.x + blockIdx.x;
  if ((nwg & 7u) == 0u) {
    unsigned cpx = nwg >> 3;
    wg = (wg & 7u) * cpx + (wg >> 3);
  }
  const long m0 = (long)(wg % gridDim.x) * 128;
  const long n0 = (long)(wg / gridDim.x) * 128;

  const int lrow = l & 15, lk = (l >> 4) * 8;

  f32x4 acc[4][4] = {};

  const int c0 = tid, c1 = tid + 256;
  const int r0 = c0 >> 2, g0 = (c0 & 3) * 8;
  const int r1 = c1 >> 2, g1 = (c1 & 3) * 8;

  for (int k0 = 0; k0 < Kpad; k0 += 32) {
    gload_lds16(A + (m0 + r0) * lda + k0 + g0, As + c0 * 8);
    gload_lds16(A + (m0 + r1) * lda + k0 + g1, As + c1 * 8);
    gload_lds16(B + (n0 + r0) * ldb + k0 + g0, Bs + c0 * 8);
    gload_lds16(B + (n0 + r1) * ldb + k0 + g1, Bs + c1 * 8);
    __syncthreads();

    bf16x8 af[4], bfr[4];
#pragma unroll
    for (int mi = 0; mi < 4; mi++)
      af[mi] = *(const bf16x8*)(As + (wr * 64 + mi * 16 + lrow) * 32 + lk);
#pragma unroll
    for (int ni = 0; ni < 4; ni++)
      bfr[ni] = *(const bf16x8*)(Bs + (wc * 64 + ni * 16 + lrow) * 32 + lk);
#pragma unroll
    for (int mi = 0; mi < 4; mi++)
#pragma unroll
      for (int ni = 0; ni < 4; ni++)
        acc[mi][ni] = __builtin_amdgcn_mfma_f32_16x16x32_bf16(af[mi], bfr[ni], acc[mi][ni], 0, 0, 0);
    __syncthreads();
  }

  const int rbase = (l >> 4) * 4;
#pragma unroll
  for (int ni = 0; ni < 4; ni++) {
    int gcol = (int)n0 + wc * 64 + ni * 16 + lrow;
    if (gcol < N) {
      float badd = 0.f;
      if (bias0) badd += bias0[gcol];
      if (bias1) badd += bias1[gcol];
#pragma unroll
      for (int mi = 0; mi < 4; mi++) {
#pragma unroll
        for (int r = 0; r < 4; r++) {
          long grow = m0 + wr * 64 + mi * 16 + rbase + r;
          float v = acc[mi][ni][r] + badd;
          if (F32OUT) ((float*)Cv)[grow * ldc + gcol] = v;
          else        ((ushort_t*)Cv)[grow * ldc + gcol] = f2b(v);
        }
      }
    }
  }
}

// =====================================================================
// Persistent LSTM layer: 100 steps, one kernel. 72 blocks (16-unit slices)
// x 256 thr (4 waves = 4 batch-16 tiles). Whh slice (4 gates x 16 rows x
// 1152) staged ONCE into 144KB dynamic LDS with chunk-XOR swizzle; cell
// state lives in registers (lane-owned); gates are lane-local (no LDS
// exchange). One weak grid barrier per step.
// =====================================================================
__global__ __launch_bounds__(256) void lstm_layer(
    ushort_t* __restrict__ hs,        // [101][64][1152] bf16
    const ushort_t* __restrict__ G,   // [6400][4608] bf16 (x@Wih^T + biases)
    const ushort_t* __restrict__ Whh, // padded [4608][1152] bf16
    const float* __restrict__ c_in,   // [64][1150] f32 initial cell
    unsigned* __restrict__ bar)
{
  extern __shared__ ushort_t Bsh[];   // 4*16*144 chunks of 16B = 147456 B
  const int tid = threadIdx.x;
  const int w = tid >> 6, l = tid & 63;
  const int us = blockIdx.x;              // unit slice [0,72)
  const int lrow = l & 15, hi = l >> 4, lk = hi * 8;
  const int u = us * 16 + lrow;
  const int row0 = w * 16 + hi * 4;       // first batch row of this lane's D regs
  const int x7 = lrow & 7;

  // ---- stage Whh slice into LDS (once), chunk-swizzled: phys = c ^ (row&7) ----
  for (int ci = tid; ci < 9216; ci += 256) {
    int gate = ci / 2304;
    int rem  = ci - gate * 2304;
    int row  = rem / 144;
    int c    = rem - row * 144;
    bf16x8 v = *(const bf16x8*)(Whh + ((long)(gate * 1150 + us * 16 + row)) * 1152 + c * 8);
    *(bf16x8*)(Bsh + (((gate * 16 + row) * 144) + (c ^ (row & 7))) * 8) = v;
  }
  // per-lane LDS base for each gate's row lrow (ushort units)
  const ushort_t* Bg0 = Bsh + ((0 * 16 + lrow) * 144) * 8;
  const ushort_t* Bg1 = Bsh + ((1 * 16 + lrow) * 144) * 8;
  const ushort_t* Bg2 = Bsh + ((2 * 16 + lrow) * 144) * 8;
  const ushort_t* Bg3 = Bsh + ((3 * 16 + lrow) * 144) * 8;

  // ---- cell state in registers (lane owns rows row0..row0+3, col u) ----
  f32x4 cc = {};
  if (u < 1150) {
#pragma unroll
    for (int r = 0; r < 4; ++r) cc[r] = c_in[(row0 + r) * 1150 + u];
  }
  __syncthreads();   // LDS staging visible

  for (int t = 0; t < 100; ++t) {
    const ushort_t* hp = hs + (long)t * 73728 + (long)(w * 16 + lrow) * 1152 + lk;
    f32x4 a0 = {}, a1 = {}, a2 = {}, a3 = {};
#pragma unroll
    for (int kc = 0; kc < 36; ++kc) {
      bf16x8 a = *(const bf16x8*)(hp + kc * 32);
      int pc8 = ((kc * 4 + hi) ^ x7) * 8;
      a0 = __builtin_amdgcn_mfma_f32_16x16x32_bf16(a, *(const bf16x8*)(Bg0 + pc8), a0, 0, 0, 0);
      a1 = __builtin_amdgcn_mfma_f32_16x16x32_bf16(a, *(const bf16x8*)(Bg1 + pc8), a1, 0, 0, 0);
      a2 = __builtin_amdgcn_mfma_f32_16x16x32_bf16(a, *(const bf16x8*)(Bg2 + pc8), a2, 0, 0, 0);
      a3 = __builtin_amdgcn_mfma_f32_16x16x32_bf16(a, *(const bf16x8*)(Bg3 + pc8), a3, 0, 0, 0);
    }

    if (u < 1150) {
#pragma unroll
      for (int r = 0; r < 4; ++r) {
        int b = row0 + r;
        long grow = ((long)t * 64 + b) * 4608;
        float iv = a0[r] + b2f(G[grow + u]);
        float fv = a1[r] + b2f(G[grow + 1150 + u]);
        float gv = a2[r] + b2f(G[grow + 2300 + u]);
        float ov = a3[r] + b2f(G[grow + 3450 + u]);
        float cn = sigm(fv) * cc[r] + sigm(iv) * tanhfast(gv);
        cc[r] = cn;
        float hv = sigm(ov) * tanhfast(cn);
        hs[(long)(t + 1) * 73728 + (long)b * 1152 + u] = f2b(hv);
      }
    }
    if (t != 99) grid_barrier_weak(bar, (unsigned)(t + 1) * 72u);
  }
}

// =====================================================================
// Fused causal attention for one (t,b): scores -> softmax -> PV. f32 math.
// =====================================================================
__global__ __launch_bounds__(256) void attn_kernel(
    const ushort_t* __restrict__ hs2,  // base at hs[1]: [100][64][1152] bf16
    ushort_t* __restrict__ outp)       // [6400][1152] bf16
{
  __shared__ float qf[1152];
  __shared__ float sc[104];
  __shared__ float sinv;
  const int rowi = blockIdx.x;  // t*64 + b
  const int t = rowi >> 6, b = rowi & 63;
  const int tid = threadIdx.x;
  const int w = tid >> 6, l = tid & 63;

  const ushort_t* q = hs2 + (long)rowi * 1152;
  for (int c = tid; c < 1150; c += 256) qf[c] = b2f(q[c]);
  __syncthreads();

  for (int s = w; s <= t; s += 4) {
    const ushort_t* k = hs2 + (long)(s * 64 + b) * 1152;
    float p = 0.f;
    for (int h = l; h < 1150; h += 64) p += qf[h] * b2f(k[h]);
    for (int off = 32; off; off >>= 1) p += __shfl_down(p, off);
    if (l == 0) sc[s] = p;
  }
  __syncthreads();

  if (w == 0) {
    float m = -1e30f;
    for (int s = l; s <= t; s += 64) m = fmaxf(m, sc[s]);
    for (int off = 32; off; off >>= 1) m = fmaxf(m, __shfl_down(m, off));
    m = __shfl(m, 0);
    float sum = 0.f;
    for (int s = l; s <= t; s += 64) { float e = __expf(sc[s] - m); sc[s] = e; sum += e; }
    for (int off = 32; off; off >>= 1) sum += __shfl_down(sum, off);
    if (l == 0) sinv = 1.f / sum;
  }
  __syncthreads();

  const float si = sinv;
  for (int h = tid; h < 1150; h += 256) {
    float a = 0.f;
    for (int s = 0; s <= t; s++) a += sc[s] * b2f(hs2[(long)(s * 64 + b) * 1152 + h]);
    outp[(long)rowi * 1152 + h] = f2b(a * si);
  }
  if (tid < 2) outp[(long)rowi * 1152 + 1150 + tid] = 0;  // zero K-pad for decoder
}

// ---------- f32 -> bf16 conversion helpers ----------
__global__ void embed_kernel(const int* __restrict__ in1, const int* __restrict__ in2,
                             const float* __restrict__ emb, ushort_t* __restrict__ x0)
{
  int rowi = blockIdx.x;
  int l = threadIdx.x;    // 64 threads
  long r1 = (long)in1[rowi] * 400, r2 = (long)in2[rowi] * 400;
  ushort_t* d = x0 + (long)rowi * 800;
  for (int c = l; c < 800; c += 64)
    d[c] = f2b(c < 400 ? emb[r1 + c] : emb[r2 + c - 400]);
}

__global__ void pad_convert(const float* __restrict__ in, ushort_t* __restrict__ out,
                            int R, int Cin, int total, int Cp)
{
  int idx = blockIdx.x * 256 + threadIdx.x;
  if (idx >= total) return;
  int r = idx / Cp, c = idx - r * Cp;
  float v = (r < R && c < Cin) ? in[(long)r * Cin + c] : 0.f;
  out[idx] = f2b(v);
}

__global__ void init_state(const float* __restrict__ h_in,
                           ushort_t* __restrict__ hs, unsigned* __restrict__ bar)
{
  int idx = blockIdx.x * 256 + threadIdx.x;  // grid covers 64*1152 = 73728
  if (idx == 0) *bar = 0u;                   // reset grid barrier for this layer
  if (idx < 64 * 1152) {
    int b = idx / 1152, c = idx - b * 1152;
    hs[idx] = (c < 1150) ? f2b(h_in[b * 1150 + c]) : (ushort_t)0;
  }
  if (idx < 100 * 128) {  // zero K-pad cols of hs rows 1..100
    int t = idx >> 7, r = idx & 127, b = r >> 1, k = r & 1;
    hs[(long)(t + 1) * 73728 + b * 1152 + 1150 + k] = 0;
  }
}

// =====================================================================
extern "C" void kernel_launch(void* const* d_in, const int* in_sizes, int n_in,
                              void* d_out, int out_size, void* d_ws, size_t ws_size,
                              hipStream_t stream) {
  (void)in_sizes; (void)n_in; (void)out_size; (void)ws_size;
  const int* input  = (const int*)d_in[0];
  const int* input2 = (const int*)d_in[1];
  const float* h_in[3] = {(const float*)d_in[2], (const float*)d_in[4], (const float*)d_in[6]};
  const float* c_in[3] = {(const float*)d_in[3], (const float*)d_in[5], (const float*)d_in[7]};
  const float* emb_W = (const float*)d_in[8];
  const float* W_ih[3] = {(const float*)d_in[9],  (const float*)d_in[13], (const float*)d_in[17]};
  const float* W_hh[3] = {(const float*)d_in[10], (const float*)d_in[14], (const float*)d_in[18]};
  const float* b_ih[3] = {(const float*)d_in[11], (const float*)d_in[15], (const float*)d_in[19]};
  const float* b_hh[3] = {(const float*)d_in[12], (const float*)d_in[16], (const float*)d_in[20]};
  const float* dec_W = (const float*)d_in[21];
  const float* dec_b = (const float*)d_in[22];
  float* out = (float*)d_out;

  // allow 144KB dynamic LDS for the persistent LSTM kernel
  hipFuncSetAttribute((const void*)lstm_layer,
                      hipFuncAttributeMaxDynamicSharedMemorySize, 147456);

  // ---- workspace: buffers alive during the final decoder GEMM + barrier ----
  char* base = (char*)d_ws;
  size_t off = 0;
  auto walloc = [&](size_t bytes) { char* r = base + off; off += (bytes + 255) & ~(size_t)255; return r; };
  ushort_t* decWp = (ushort_t*)walloc(33280ull * 1152 * 2);   // 76,677,120
  ushort_t* attnB = (ushort_t*)walloc(6400ull * 1152 * 2);    // 14,745,600
  unsigned* bar   = (unsigned*)walloc(256);

  // ---- layer-phase scratch inside d_out (852 MB f32; scratch uses first
  //      ~120 MB, all dead before the decoder GEMM which reads only ws). ----
  char* ob = (char*)d_out;
  ushort_t* G   = (ushort_t*)(ob + 0);            // 58,982,400
  ushort_t* x0  = (ushort_t*)(ob + 58982400);     // 10,240,000
  ushort_t* Wp  = (ushort_t*)(ob + 69222400);     // 10,616,832
  ushort_t* Whp = (ushort_t*)(ob + 79839232);     // 10,616,832
  ushort_t* hsA = (ushort_t*)(ob + 90456064);     // 14,893,056
  ushort_t* hsB = (ushort_t*)(ob + 105349120);    // -> end 120,242,176

  embed_kernel<<<6400, 64, 0, stream>>>(input, input2, emb_W, x0);

  ushort_t* hcur[3] = {hsA, hsB, hsA};
  const ushort_t* X = x0;
  int lda = 800, Kp = 800;
  for (int lyr = 0; lyr < 3; lyr++) {
    if (lyr == 0) {
      int tot = 4608 * 800;
      pad_convert<<<(tot + 255) / 256, 256, 0, stream>>>(W_ih[0], Wp, 4600, 800, tot, 800);
    } else {
      int tot = 4608 * 1152;
      pad_convert<<<(tot + 255) / 256, 256, 0, stream>>>(W_ih[lyr], Wp, 4600, 1150, tot, 1152);
    }
    {
      int tot = 4608 * 1152;
      pad_convert<<<(tot + 255) / 256, 256, 0, stream>>>(W_hh[lyr], Whp, 4600, 1150, tot, 1152);
    }
    gemm_bt<false><<<dim3(50, 36), 256, 0, stream>>>(X, Wp, (void*)G, b_ih[lyr], b_hh[lyr],
                                                     lda, Kp, 4608, Kp, 4600);
    init_state<<<288, 256, 0, stream>>>(h_in[lyr], hcur[lyr], bar);
    lstm_layer<<<72, 256, 147456, stream>>>(hcur[lyr], G, Whp, c_in[lyr], bar);
    X = hcur[lyr] + 73728;
    lda = 1152; Kp = 1152;
  }

  attn_kernel<<<6400, 256, 0, stream>>>(hsA + 73728, attnB);

  {
    int tot = 33280 * 1152;
    pad_convert<<<(tot + 255) / 256, 256, 0, stream>>>(dec_W, decWp, 33278, 1150, tot, 1152);
  }

  gemm_bt<true><<<dim3(50, 260), 256, 0, stream>>>(attnB, decWp, (void*)out, dec_b, nullptr,
                                                   1152, 1152, 33278, 1152, 33278);
}

// Round 7
// 5261.891 us; speedup vs baseline: 2.1055x; 1.1396x over previous
//
#include <hip/hip_runtime.h>
#include <stdint.h>

typedef unsigned short ushort_t;
typedef __bf16 bf16x8 __attribute__((ext_vector_type(8)));
typedef float f32x4 __attribute__((ext_vector_type(4)));

// ---------- bf16 <-> f32 (bit ops) ----------
__device__ __forceinline__ float b2f(ushort_t u) {
  union { unsigned u; float f; } v; v.u = ((unsigned)u) << 16; return v.f;
}
__device__ __forceinline__ ushort_t f2b(float f) {
  union { float f; unsigned u; } v; v.f = f;
  unsigned r = (v.u + 0x7FFFu + ((v.u >> 16) & 1u)) >> 16;
  return (ushort_t)r;
}

// ---------- fast transcendentals (HW v_exp_f32 based) ----------
__device__ __forceinline__ float sigm(float x)     { return 1.f / (1.f + __expf(-x)); }
__device__ __forceinline__ float tanhfast(float x) { return 1.f - 2.f / (1.f + __expf(2.f * x)); }

// ---------- device-coherent write-through 2B store (sc0 sc1: goes to MALL
// coherence point; leaves no dirty L2 line -> no wbl2 fence needed) ----------
__device__ __forceinline__ void store_short_wt(ushort_t* p, ushort_t v) {
  asm volatile("global_store_short %0, %1, off sc0 sc1"
               :: "v"(p), "v"((unsigned)v) : "memory");
}

// ---------- global -> LDS direct load, 16B per lane ----------
__device__ __forceinline__ void gload_lds16(const void* g, void* lds) {
  auto l3 = reinterpret_cast<__attribute__((address_space(3))) unsigned*>(
      reinterpret_cast<uintptr_t>(lds));
  __builtin_amdgcn_global_load_lds(reinterpret_cast<const unsigned*>(g), l3, 16, 0, 0);
}

// ---------- fence-free grid barrier. Preceding __syncthreads() drains each
// wave's vmcnt (compiler emits s_waitcnt vmcnt(0) before s_barrier), which
// completes the write-through h-stores to the coherence point. No
// acquire-invalidate: consumers only read addresses freshly produced this
// step (never stale-cached). Whh/G stay L2-resident; no wbl2 tag walks. ----
__device__ __forceinline__ void grid_barrier_wt(unsigned* bar, unsigned target) {
  __syncthreads();                 // drains vmcnt of ALL waves, then s_barrier
  if (threadIdx.x == 0) {
    __hip_atomic_fetch_add(bar, 1u, __ATOMIC_RELAXED, __HIP_MEMORY_SCOPE_AGENT);
    while (__hip_atomic_load(bar, __ATOMIC_RELAXED, __HIP_MEMORY_SCOPE_AGENT) < target)
      __builtin_amdgcn_s_sleep(2);
  }
  __syncthreads();
  asm volatile("" ::: "memory");   // no reordering of h-loads above the barrier
}

// =====================================================================
// GEMM: C[M,N] = A[M,K] @ B[N,K]^T + bias0 + bias1 (bf16 in, f32 acc,
// bf16 or f32 out). BM=BN=128, BK=32, 256 thr (4 waves), global_load_lds
// staging + bijective XCD swizzle when nwg%8==0.
// =====================================================================
template <bool F32OUT>
__global__ __launch_bounds__(256) void gemm_bt(
    const ushort_t* __restrict__ A, const ushort_t* __restrict__ B,
    void* __restrict__ Cv,
    const float* __restrict__ bias0, const float* __restrict__ bias1,
    int lda, int ldb, int ldc, int Kpad, int N)
{
  __shared__ alignas(16) ushort_t As[128 * 32];
  __shared__ alignas(16) ushort_t Bs[128 * 32];
  const int tid = threadIdx.x;
  const int w = tid >> 6, l = tid & 63;
  const int wr = w >> 1, wc = w & 1;

  unsigned nwg = gridDim.x * gridDim.y;
  unsigned wg = blockIdx.y * gridDim.x + blockIdx.x;
  if ((nwg & 7u) == 0u) {
    unsigned cpx = nwg >> 3;
    wg = (wg & 7u) * cpx + (wg >> 3);
  }
  const long m0 = (long)(wg % gridDim.x) * 128;
  const long n0 = (long)(wg / gridDim.x) * 128;

  const int lrow = l & 15, lk = (l >> 4) * 8;

  f32x4 acc[4][4] = {};

  const int c0 = tid, c1 = tid + 256;
  const int r0 = c0 >> 2, g0 = (c0 & 3) * 8;
  const int r1 = c1 >> 2, g1 = (c1 & 3) * 8;

  for (int k0 = 0; k0 < Kpad; k0 += 32) {
    gload_lds16(A + (m0 + r0) * lda + k0 + g0, As + c0 * 8);
    gload_lds16(A + (m0 + r1) * lda + k0 + g1, As + c1 * 8);
    gload_lds16(B + (n0 + r0) * ldb + k0 + g0, Bs + c0 * 8);
    gload_lds16(B + (n0 + r1) * ldb + k0 + g1, Bs + c1 * 8);
    __syncthreads();

    bf16x8 af[4], bfr[4];
#pragma unroll
    for (int mi = 0; mi < 4; mi++)
      af[mi] = *(const bf16x8*)(As + (wr * 64 + mi * 16 + lrow) * 32 + lk);
#pragma unroll
    for (int ni = 0; ni < 4; ni++)
      bfr[ni] = *(const bf16x8*)(Bs + (wc * 64 + ni * 16 + lrow) * 32 + lk);
#pragma unroll
    for (int mi = 0; mi < 4; mi++)
#pragma unroll
      for (int ni = 0; ni < 4; ni++)
        acc[mi][ni] = __builtin_amdgcn_mfma_f32_16x16x32_bf16(af[mi], bfr[ni], acc[mi][ni], 0, 0, 0);
    __syncthreads();
  }

  const int rbase = (l >> 4) * 4;
#pragma unroll
  for (int ni = 0; ni < 4; ni++) {
    int gcol = (int)n0 + wc * 64 + ni * 16 + lrow;
    if (gcol < N) {
      float badd = 0.f;
      if (bias0) badd += bias0[gcol];
      if (bias1) badd += bias1[gcol];
#pragma unroll
      for (int mi = 0; mi < 4; mi++) {
#pragma unroll
        for (int r = 0; r < 4; r++) {
          long grow = m0 + wr * 64 + mi * 16 + rbase + r;
          float v = acc[mi][ni][r] + badd;
          if (F32OUT) ((float*)Cv)[grow * ldc + gcol] = v;
          else        ((ushort_t*)Cv)[grow * ldc + gcol] = f2b(v);
        }
      }
    }
  }
}

// =====================================================================
// Persistent LSTM layer: 100 steps, one kernel. 72 blocks (16-unit slices)
// x 256 thr (4 waves = 4 batch-16 tiles). Whh slice staged once in 144KB
// LDS (chunk-XOR swizzle); cell state in registers; G prefetched into regs
// at step start; h published via write-through stores; fence-free barrier.
// =====================================================================
__global__ __launch_bounds__(256) void lstm_layer(
    ushort_t* __restrict__ hs,        // [101][64][1152] bf16
    const ushort_t* __restrict__ G,   // [6400][4608] bf16 (x@Wih^T + biases)
    const ushort_t* __restrict__ Whh, // padded [4608][1152] bf16
    const float* __restrict__ c_in,   // [64][1150] f32 initial cell
    unsigned* __restrict__ bar)
{
  extern __shared__ ushort_t Bsh[];   // 4*16*144 chunks of 16B = 147456 B
  const int tid = threadIdx.x;
  const int w = tid >> 6, l = tid & 63;
  const int us = blockIdx.x;              // unit slice [0,72)
  const int lrow = l & 15, hi = l >> 4, lk = hi * 8;
  const int u = us * 16 + lrow;
  const int usafe = (u < 1150) ? u : 0;
  const int row0 = w * 16 + hi * 4;       // first batch row of this lane's D regs
  const int x7 = lrow & 7;

  // ---- stage Whh slice into LDS (once), chunk-swizzled: phys = c ^ (row&7) ----
  for (int ci = tid; ci < 9216; ci += 256) {
    int gate = ci / 2304;
    int rem  = ci - gate * 2304;
    int row  = rem / 144;
    int c    = rem - row * 144;
    bf16x8 v = *(const bf16x8*)(Whh + ((long)(gate * 1150 + us * 16 + row)) * 1152 + c * 8);
    *(bf16x8*)(Bsh + (((gate * 16 + row) * 144) + (c ^ (row & 7))) * 8) = v;
  }
  const ushort_t* Bg0 = Bsh + ((0 * 16 + lrow) * 144) * 8;
  const ushort_t* Bg1 = Bsh + ((1 * 16 + lrow) * 144) * 8;
  const ushort_t* Bg2 = Bsh + ((2 * 16 + lrow) * 144) * 8;
  const ushort_t* Bg3 = Bsh + ((3 * 16 + lrow) * 144) * 8;

  // ---- cell state in registers (lane owns rows row0..row0+3, col u) ----
  f32x4 cc = {};
  if (u < 1150) {
#pragma unroll
    for (int r = 0; r < 4; ++r) cc[r] = c_in[(row0 + r) * 1150 + u];
  }
  __syncthreads();   // LDS staging visible

  for (int t = 0; t < 100; ++t) {
    // prefetch this step's 16 G gate values (independent of h -> latency
    // hides under the MFMA chain)
    ushort_t gv[16];
    {
      const ushort_t* gp = G + ((long)t * 64 + row0) * 4608 + usafe;
#pragma unroll
      for (int r = 0; r < 4; ++r)
#pragma unroll
        for (int g = 0; g < 4; ++g)
          gv[r * 4 + g] = gp[(long)r * 4608 + g * 1150];
    }

    const ushort_t* hp = hs + (long)t * 73728 + (long)(w * 16 + lrow) * 1152 + lk;
    f32x4 a0 = {}, a1 = {}, a2 = {}, a3 = {};
#pragma unroll
    for (int kc = 0; kc < 36; ++kc) {
      bf16x8 a = *(const bf16x8*)(hp + kc * 32);
      int pc8 = ((kc * 4 + hi) ^ x7) * 8;
      a0 = __builtin_amdgcn_mfma_f32_16x16x32_bf16(a, *(const bf16x8*)(Bg0 + pc8), a0, 0, 0, 0);
      a1 = __builtin_amdgcn_mfma_f32_16x16x32_bf16(a, *(const bf16x8*)(Bg1 + pc8), a1, 0, 0, 0);
      a2 = __builtin_amdgcn_mfma_f32_16x16x32_bf16(a, *(const bf16x8*)(Bg2 + pc8), a2, 0, 0, 0);
      a3 = __builtin_amdgcn_mfma_f32_16x16x32_bf16(a, *(const bf16x8*)(Bg3 + pc8), a3, 0, 0, 0);
    }

    if (u < 1150) {
#pragma unroll
      for (int r = 0; r < 4; ++r) {
        float iv = a0[r] + b2f(gv[r * 4 + 0]);
        float fv = a1[r] + b2f(gv[r * 4 + 1]);
        float gg = a2[r] + b2f(gv[r * 4 + 2]);
        float ov = a3[r] + b2f(gv[r * 4 + 3]);
        float cn = sigm(fv) * cc[r] + sigm(iv) * tanhfast(gg);
        cc[r] = cn;
        float hv = sigm(ov) * tanhfast(cn);
        store_short_wt(hs + (long)(t + 1) * 73728 + (long)(row0 + r) * 1152 + u, f2b(hv));
      }
    }
    if (t != 99) grid_barrier_wt(bar, (unsigned)(t + 1) * 72u);
  }
}

// =====================================================================
// Fused causal attention for one (t,b): scores -> softmax -> PV. f32 math.
// =====================================================================
__global__ __launch_bounds__(256) void attn_kernel(
    const ushort_t* __restrict__ hs2,  // base at hs[1]: [100][64][1152] bf16
    ushort_t* __restrict__ outp)       // [6400][1152] bf16
{
  __shared__ float qf[1152];
  __shared__ float sc[104];
  __shared__ float sinv;
  const int rowi = blockIdx.x;  // t*64 + b
  const int t = rowi >> 6, b = rowi & 63;
  const int tid = threadIdx.x;
  const int w = tid >> 6, l = tid & 63;

  const ushort_t* q = hs2 + (long)rowi * 1152;
  for (int c = tid; c < 1150; c += 256) qf[c] = b2f(q[c]);
  __syncthreads();

  for (int s = w; s <= t; s += 4) {
    const ushort_t* k = hs2 + (long)(s * 64 + b) * 1152;
    float p = 0.f;
    for (int h = l; h < 1150; h += 64) p += qf[h] * b2f(k[h]);
    for (int off = 32; off; off >>= 1) p += __shfl_down(p, off);
    if (l == 0) sc[s] = p;
  }
  __syncthreads();

  if (w == 0) {
    float m = -1e30f;
    for (int s = l; s <= t; s += 64) m = fmaxf(m, sc[s]);
    for (int off = 32; off; off >>= 1) m = fmaxf(m, __shfl_down(m, off));
    m = __shfl(m, 0);
    float sum = 0.f;
    for (int s = l; s <= t; s += 64) { float e = __expf(sc[s] - m); sc[s] = e; sum += e; }
    for (int off = 32; off; off >>= 1) sum += __shfl_down(sum, off);
    if (l == 0) sinv = 1.f / sum;
  }
  __syncthreads();

  const float si = sinv;
  for (int h = tid; h < 1150; h += 256) {
    float a = 0.f;
    for (int s = 0; s <= t; s++) a += sc[s] * b2f(hs2[(long)(s * 64 + b) * 1152 + h]);
    outp[(long)rowi * 1152 + h] = f2b(a * si);
  }
  if (tid < 2) outp[(long)rowi * 1152 + 1150 + tid] = 0;  // zero K-pad for decoder
}

// ---------- f32 -> bf16 conversion helpers ----------
__global__ void embed_kernel(const int* __restrict__ in1, const int* __restrict__ in2,
                             const float* __restrict__ emb, ushort_t* __restrict__ x0)
{
  int rowi = blockIdx.x;
  int l = threadIdx.x;    // 64 threads
  long r1 = (long)in1[rowi] * 400, r2 = (long)in2[rowi] * 400;
  ushort_t* d = x0 + (long)rowi * 800;
  for (int c = l; c < 800; c += 64)
    d[c] = f2b(c < 400 ? emb[r1 + c] : emb[r2 + c - 400]);
}

__global__ void pad_convert(const float* __restrict__ in, ushort_t* __restrict__ out,
                            int R, int Cin, int total, int Cp)
{
  int idx = blockIdx.x * 256 + threadIdx.x;
  if (idx >= total) return;
  int r = idx / Cp, c = idx - r * Cp;
  float v = (r < R && c < Cin) ? in[(long)r * Cin + c] : 0.f;
  out[idx] = f2b(v);
}

__global__ void init_state(const float* __restrict__ h_in,
                           ushort_t* __restrict__ hs, unsigned* __restrict__ bar)
{
  int idx = blockIdx.x * 256 + threadIdx.x;  // grid covers 64*1152 = 73728
  if (idx == 0) *bar = 0u;                   // reset grid barrier for this layer
  if (idx < 64 * 1152) {
    int b = idx / 1152, c = idx - b * 1152;
    hs[idx] = (c < 1150) ? f2b(h_in[b * 1150 + c]) : (ushort_t)0;
  }
  if (idx < 100 * 128) {  // zero K-pad cols of hs rows 1..100
    int t = idx >> 7, r = idx & 127, b = r >> 1, k = r & 1;
    hs[(long)(t + 1) * 73728 + b * 1152 + 1150 + k] = 0;
  }
}

// =====================================================================
extern "C" void kernel_launch(void* const* d_in, const int* in_sizes, int n_in,
                              void* d_out, int out_size, void* d_ws, size_t ws_size,
                              hipStream_t stream) {
  (void)in_sizes; (void)n_in; (void)out_size; (void)ws_size;
  const int* input  = (const int*)d_in[0];
  const int* input2 = (const int*)d_in[1];
  const float* h_in[3] = {(const float*)d_in[2], (const float*)d_in[4], (const float*)d_in[6]};
  const float* c_in[3] = {(const float*)d_in[3], (const float*)d_in[5], (const float*)d_in[7]};
  const float* emb_W = (const float*)d_in[8];
  const float* W_ih[3] = {(const float*)d_in[9],  (const float*)d_in[13], (const float*)d_in[17]};
  const float* W_hh[3] = {(const float*)d_in[10], (const float*)d_in[14], (const float*)d_in[18]};
  const float* b_ih[3] = {(const float*)d_in[11], (const float*)d_in[15], (const float*)d_in[19]};
  const float* b_hh[3] = {(const float*)d_in[12], (const float*)d_in[16], (const float*)d_in[20]};
  const float* dec_W = (const float*)d_in[21];
  const float* dec_b = (const float*)d_in[22];
  float* out = (float*)d_out;

  // allow 144KB dynamic LDS for the persistent LSTM kernel
  hipFuncSetAttribute((const void*)lstm_layer,
                      hipFuncAttributeMaxDynamicSharedMemorySize, 147456);

  // ---- workspace: buffers alive during the final decoder GEMM + barrier ----
  char* base = (char*)d_ws;
  size_t off = 0;
  auto walloc = [&](size_t bytes) { char* r = base + off; off += (bytes + 255) & ~(size_t)255; return r; };
  ushort_t* decWp = (ushort_t*)walloc(33280ull * 1152 * 2);   // 76,677,120
  ushort_t* attnB = (ushort_t*)walloc(6400ull * 1152 * 2);    // 14,745,600
  unsigned* bar   = (unsigned*)walloc(256);

  // ---- layer-phase scratch inside d_out (852 MB f32; scratch uses first
  //      ~120 MB, all dead before the decoder GEMM which reads only ws). ----
  char* ob = (char*)d_out;
  ushort_t* G   = (ushort_t*)(ob + 0);            // 58,982,400
  ushort_t* x0  = (ushort_t*)(ob + 58982400);     // 10,240,000
  ushort_t* Wp  = (ushort_t*)(ob + 69222400);     // 10,616,832
  ushort_t* Whp = (ushort_t*)(ob + 79839232);     // 10,616,832
  ushort_t* hsA = (ushort_t*)(ob + 90456064);     // 14,893,056
  ushort_t* hsB = (ushort_t*)(ob + 105349120);    // -> end 120,242,176

  embed_kernel<<<6400, 64, 0, stream>>>(input, input2, emb_W, x0);

  ushort_t* hcur[3] = {hsA, hsB, hsA};
  const ushort_t* X = x0;
  int lda = 800, Kp = 800;
  for (int lyr = 0; lyr < 3; lyr++) {
    if (lyr == 0) {
      int tot = 4608 * 800;
      pad_convert<<<(tot + 255) / 256, 256, 0, stream>>>(W_ih[0], Wp, 4600, 800, tot, 800);
    } else {
      int tot = 4608 * 1152;
      pad_convert<<<(tot + 255) / 256, 256, 0, stream>>>(W_ih[lyr], Wp, 4600, 1150, tot, 1152);
    }
    {
      int tot = 4608 * 1152;
      pad_convert<<<(tot + 255) / 256, 256, 0, stream>>>(W_hh[lyr], Whp, 4600, 1150, tot, 1152);
    }
    gemm_bt<false><<<dim3(50, 36), 256, 0, stream>>>(X, Wp, (void*)G, b_ih[lyr], b_hh[lyr],
                                                     lda, Kp, 4608, Kp, 4600);
    init_state<<<288, 256, 0, stream>>>(h_in[lyr], hcur[lyr], bar);
    lstm_layer<<<72, 256, 147456, stream>>>(hcur[lyr], G, Whp, c_in[lyr], bar);
    X = hcur[lyr] + 73728;
    lda = 1152; Kp = 1152;
  }

  attn_kernel<<<6400, 256, 0, stream>>>(hsA + 73728, attnB);

  {
    int tot = 33280 * 1152;
    pad_convert<<<(tot + 255) / 256, 256, 0, stream>>>(dec_W, decWp, 33278, 1150, tot, 1152);
  }

  gemm_bt<true><<<dim3(50, 260), 256, 0, stream>>>(attnB, decWp, (void*)out, dec_b, nullptr,
                                                   1152, 1152, 33278, 1152, 33278);
}

// Round 8
// 4998.276 us; speedup vs baseline: 2.2166x; 1.0527x over previous
//
#include <hip/hip_runtime.h>
#include <stdint.h>

typedef unsigned short ushort_t;
typedef __bf16 bf16x8 __attribute__((ext_vector_type(8)));
typedef float f32x4 __attribute__((ext_vector_type(4)));

// ---------- bf16 <-> f32 (bit ops) ----------
__device__ __forceinline__ float b2f(ushort_t u) {
  union { unsigned u; float f; } v; v.u = ((unsigned)u) << 16; return v.f;
}
__device__ __forceinline__ ushort_t f2b(float f) {
  union { float f; unsigned u; } v; v.f = f;
  unsigned r = (v.u + 0x7FFFu + ((v.u >> 16) & 1u)) >> 16;
  return (ushort_t)r;
}

// ---------- fast transcendentals (HW v_exp_f32 based) ----------
__device__ __forceinline__ float sigm(float x)     { return 1.f / (1.f + __expf(-x)); }
__device__ __forceinline__ float tanhfast(float x) { return 1.f - 2.f / (1.f + __expf(2.f * x)); }

// ---------- device-coherent write-through stores (to MALL; no dirty L2) ----
__device__ __forceinline__ void store_short_wt(ushort_t* p, ushort_t v) {
  asm volatile("global_store_short %0, %1, off sc0 sc1"
               :: "v"(p), "v"((unsigned)v) : "memory");
}
__device__ __forceinline__ void store_uint_wt(unsigned* p, unsigned v) {
  asm volatile("global_store_dword %0, %1, off sc0 sc1"
               :: "v"(p), "v"(v) : "memory");
}

// ---------- global -> LDS direct load, 16B per lane ----------
__device__ __forceinline__ void gload_lds16(const void* g, void* lds) {
  auto l3 = reinterpret_cast<__attribute__((address_space(3))) unsigned*>(
      reinterpret_cast<uintptr_t>(lds));
  __builtin_amdgcn_global_load_lds(reinterpret_cast<const unsigned*>(g), l3, 16, 0, 0);
}

// =====================================================================
// GEMM: C[M,N] = A[M,K] @ B[N,K]^T + bias0 + bias1 (bf16 in, f32 acc,
// bf16 or f32 out). BM=BN=128, BK=32, 256 thr (4 waves), global_load_lds
// staging + bijective XCD swizzle when nwg%8==0.
// =====================================================================
template <bool F32OUT>
__global__ __launch_bounds__(256) void gemm_bt(
    const ushort_t* __restrict__ A, const ushort_t* __restrict__ B,
    void* __restrict__ Cv,
    const float* __restrict__ bias0, const float* __restrict__ bias1,
    int lda, int ldb, int ldc, int Kpad, int N)
{
  __shared__ alignas(16) ushort_t As[128 * 32];
  __shared__ alignas(16) ushort_t Bs[128 * 32];
  const int tid = threadIdx.x;
  const int w = tid >> 6, l = tid & 63;
  const int wr = w >> 1, wc = w & 1;

  unsigned nwg = gridDim.x * gridDim.y;
  unsigned wg = blockIdx.y * gridDim.x + blockIdx.x;
  if ((nwg & 7u) == 0u) {
    unsigned cpx = nwg >> 3;
    wg = (wg & 7u) * cpx + (wg >> 3);
  }
  const long m0 = (long)(wg % gridDim.x) * 128;
  const long n0 = (long)(wg / gridDim.x) * 128;

  const int lrow = l & 15, lk = (l >> 4) * 8;

  f32x4 acc[4][4] = {};

  const int c0 = tid, c1 = tid + 256;
  const int r0 = c0 >> 2, g0 = (c0 & 3) * 8;
  const int r1 = c1 >> 2, g1 = (c1 & 3) * 8;

  for (int k0 = 0; k0 < Kpad; k0 += 32) {
    gload_lds16(A + (m0 + r0) * lda + k0 + g0, As + c0 * 8);
    gload_lds16(A + (m0 + r1) * lda + k0 + g1, As + c1 * 8);
    gload_lds16(B + (n0 + r0) * ldb + k0 + g0, Bs + c0 * 8);
    gload_lds16(B + (n0 + r1) * ldb + k0 + g1, Bs + c1 * 8);
    __syncthreads();

    bf16x8 af[4], bfr[4];
#pragma unroll
    for (int mi = 0; mi < 4; mi++)
      af[mi] = *(const bf16x8*)(As + (wr * 64 + mi * 16 + lrow) * 32 + lk);
#pragma unroll
    for (int ni = 0; ni < 4; ni++)
      bfr[ni] = *(const bf16x8*)(Bs + (wc * 64 + ni * 16 + lrow) * 32 + lk);
#pragma unroll
    for (int mi = 0; mi < 4; mi++)
#pragma unroll
      for (int ni = 0; ni < 4; ni++)
        acc[mi][ni] = __builtin_amdgcn_mfma_f32_16x16x32_bf16(af[mi], bfr[ni], acc[mi][ni], 0, 0, 0);
    __syncthreads();
  }

  const int rbase = (l >> 4) * 4;
#pragma unroll
  for (int ni = 0; ni < 4; ni++) {
    int gcol = (int)n0 + wc * 64 + ni * 16 + lrow;
    if (gcol < N) {
      float badd = 0.f;
      if (bias0) badd += bias0[gcol];
      if (bias1) badd += bias1[gcol];
#pragma unroll
      for (int mi = 0; mi < 4; mi++) {
#pragma unroll
        for (int r = 0; r < 4; r++) {
          long grow = m0 + wr * 64 + mi * 16 + rbase + r;
          float v = acc[mi][ni][r] + badd;
          if (F32OUT) ((float*)Cv)[grow * ldc + gcol] = v;
          else        ((ushort_t*)Cv)[grow * ldc + gcol] = f2b(v);
        }
      }
    }
  }
}

// =====================================================================
// Persistent LSTM layer: 100 steps, one kernel. 72 blocks (16-unit slices)
// x 256 thr (4 waves = 4 batch-16 tiles). Gate 0/1 weight fragments live in
// REGISTERS (loop-invariant, 288 VGPR); gates 2/3 staged once in 72KB LDS
// (chunk-XOR swizzle). Cell state in registers. h published write-through.
// Barrier: per-block flag lines (parallel arrival, no RMW contention);
// wave 0 polls all 72 flags; next-step G prefetch hides under the spin.
// =====================================================================
__global__ __launch_bounds__(256, 1) void lstm_layer(
    ushort_t* __restrict__ hs,        // [101][64][1152] bf16
    const ushort_t* __restrict__ G,   // [6400][4608] bf16 (x@Wih^T + biases)
    const ushort_t* __restrict__ Whh, // padded [4608][1152] bf16
    const float* __restrict__ c_in,   // [64][1150] f32 initial cell
    unsigned* __restrict__ flags)     // 72 lines of 128B
{
  extern __shared__ ushort_t Bsh[];   // gates 2,3: 2*16*144 chunks = 73728 B
  const int tid = threadIdx.x;
  const int w = tid >> 6, l = tid & 63;
  const int us = blockIdx.x;              // unit slice [0,72)
  const int lrow = l & 15, hi = l >> 4, lk = hi * 8;
  const int u = us * 16 + lrow;
  const int usafe = (u < 1150) ? u : 0;
  const int row0 = w * 16 + hi * 4;       // first batch row of this lane's D regs
  const int x7 = lrow & 7;

  // ---- stage gates 2,3 into LDS (once), chunk-swizzled: phys = c ^ (row&7) ----
  for (int ci = tid; ci < 4608; ci += 256) {
    int gate = ci / 2304;                 // 0,1 -> actual gates 2,3
    int rem  = ci - gate * 2304;
    int row  = rem / 144;
    int c    = rem - row * 144;
    bf16x8 v = *(const bf16x8*)(Whh + ((long)((gate + 2) * 1150 + us * 16 + row)) * 1152 + c * 8);
    *(bf16x8*)(Bsh + (((gate * 16 + row) * 144) + (c ^ (row & 7))) * 8) = v;
  }
  const ushort_t* Bg2 = Bsh + ((0 * 16 + lrow) * 144) * 8;
  const ushort_t* Bg3 = Bsh + ((1 * 16 + lrow) * 144) * 8;

  // ---- gates 0,1 weight fragments in registers (loop-invariant) ----
  bf16x8 w0[36], w1[36];
  {
    const ushort_t* W0p = Whh + ((long)(0 * 1150 + us * 16 + lrow)) * 1152 + lk;
    const ushort_t* W1p = Whh + ((long)(1 * 1150 + us * 16 + lrow)) * 1152 + lk;
#pragma unroll
    for (int kc = 0; kc < 36; ++kc) {
      w0[kc] = *(const bf16x8*)(W0p + kc * 32);
      w1[kc] = *(const bf16x8*)(W1p + kc * 32);
    }
  }

  // ---- cell state in registers (lane owns rows row0..row0+3, col u) ----
  f32x4 cc = {};
  if (u < 1150) {
#pragma unroll
    for (int r = 0; r < 4; ++r) cc[r] = c_in[(row0 + r) * 1150 + u];
  }

  // ---- G prefetch for t=0 ----
  ushort_t gvv[16];
  {
    const ushort_t* gp = G + ((long)0 * 64 + row0) * 4608 + usafe;
#pragma unroll
    for (int r = 0; r < 4; ++r)
#pragma unroll
      for (int g = 0; g < 4; ++g)
        gvv[r * 4 + g] = gp[(long)r * 4608 + g * 1150];
  }
  __syncthreads();   // LDS staging visible

  for (int t = 0; t < 100; ++t) {
    const ushort_t* hp = hs + (long)t * 73728 + (long)(w * 16 + lrow) * 1152 + lk;
    f32x4 a0 = {}, a1 = {}, a2 = {}, a3 = {};
#pragma unroll
    for (int kc = 0; kc < 36; ++kc) {
      bf16x8 a = *(const bf16x8*)(hp + kc * 32);
      int pc8 = ((kc * 4 + hi) ^ x7) * 8;
      a0 = __builtin_amdgcn_mfma_f32_16x16x32_bf16(a, w0[kc], a0, 0, 0, 0);
      a1 = __builtin_amdgcn_mfma_f32_16x16x32_bf16(a, w1[kc], a1, 0, 0, 0);
      a2 = __builtin_amdgcn_mfma_f32_16x16x32_bf16(a, *(const bf16x8*)(Bg2 + pc8), a2, 0, 0, 0);
      a3 = __builtin_amdgcn_mfma_f32_16x16x32_bf16(a, *(const bf16x8*)(Bg3 + pc8), a3, 0, 0, 0);
    }

    if (u < 1150) {
#pragma unroll
      for (int r = 0; r < 4; ++r) {
        float iv = a0[r] + b2f(gvv[r * 4 + 0]);
        float fv = a1[r] + b2f(gvv[r * 4 + 1]);
        float gg = a2[r] + b2f(gvv[r * 4 + 2]);
        float ov = a3[r] + b2f(gvv[r * 4 + 3]);
        float cn = sigm(fv) * cc[r] + sigm(iv) * tanhfast(gg);
        cc[r] = cn;
        float hv = sigm(ov) * tanhfast(cn);
        store_short_wt(hs + (long)(t + 1) * 73728 + (long)(row0 + r) * 1152 + u, f2b(hv));
      }
    }

    if (t != 99) {
      // ---- contention-free grid barrier ----
      asm volatile("s_waitcnt vmcnt(0)" ::: "memory");  // each wave: h-stores at MALL
      __syncthreads();
      if (tid == 0) store_uint_wt(flags + (long)us * 32, (unsigned)(t + 1));
      // prefetch next step's G while waiting (latency hides under the spin)
      {
        const ushort_t* gp = G + ((long)(t + 1) * 64 + row0) * 4608 + usafe;
#pragma unroll
        for (int r = 0; r < 4; ++r)
#pragma unroll
          for (int g = 0; g < 4; ++g)
            gvv[r * 4 + g] = gp[(long)r * 4608 + g * 1150];
      }
      if (tid < 64) {   // wave 0 polls all 72 flag lines
        const unsigned target = (unsigned)(t + 1);
        unsigned* p1 = flags + (long)tid * 32;
        unsigned* p2 = flags + (long)(64 + (tid & 7)) * 32;
        for (;;) {
          unsigned v1 = __hip_atomic_load(p1, __ATOMIC_RELAXED, __HIP_MEMORY_SCOPE_AGENT);
          unsigned v2 = __hip_atomic_load(p2, __ATOMIC_RELAXED, __HIP_MEMORY_SCOPE_AGENT);
          if (__all(v1 >= target && v2 >= target)) break;
          __builtin_amdgcn_s_sleep(1);
        }
      }
      __syncthreads();
      asm volatile("" ::: "memory");  // keep next-step h loads below the barrier
    }
  }
}

// =====================================================================
// Fused causal attention for one (t,b): scores -> softmax -> PV. f32 math.
// =====================================================================
__global__ __launch_bounds__(256) void attn_kernel(
    const ushort_t* __restrict__ hs2,  // base at hs[1]: [100][64][1152] bf16
    ushort_t* __restrict__ outp)       // [6400][1152] bf16
{
  __shared__ float qf[1152];
  __shared__ float sc[104];
  __shared__ float sinv;
  const int rowi = blockIdx.x;  // t*64 + b
  const int t = rowi >> 6, b = rowi & 63;
  const int tid = threadIdx.x;
  const int w = tid >> 6, l = tid & 63;

  const ushort_t* q = hs2 + (long)rowi * 1152;
  for (int c = tid; c < 1150; c += 256) qf[c] = b2f(q[c]);
  __syncthreads();

  for (int s = w; s <= t; s += 4) {
    const ushort_t* k = hs2 + (long)(s * 64 + b) * 1152;
    float p = 0.f;
    for (int h = l; h < 1150; h += 64) p += qf[h] * b2f(k[h]);
    for (int off = 32; off; off >>= 1) p += __shfl_down(p, off);
    if (l == 0) sc[s] = p;
  }
  __syncthreads();

  if (w == 0) {
    float m = -1e30f;
    for (int s = l; s <= t; s += 64) m = fmaxf(m, sc[s]);
    for (int off = 32; off; off >>= 1) m = fmaxf(m, __shfl_down(m, off));
    m = __shfl(m, 0);
    float sum = 0.f;
    for (int s = l; s <= t; s += 64) { float e = __expf(sc[s] - m); sc[s] = e; sum += e; }
    for (int off = 32; off; off >>= 1) sum += __shfl_down(sum, off);
    if (l == 0) sinv = 1.f / sum;
  }
  __syncthreads();

  const float si = sinv;
  for (int h = tid; h < 1150; h += 256) {
    float a = 0.f;
    for (int s = 0; s <= t; s++) a += sc[s] * b2f(hs2[(long)(s * 64 + b) * 1152 + h]);
    outp[(long)rowi * 1152 + h] = f2b(a * si);
  }
  if (tid < 2) outp[(long)rowi * 1152 + 1150 + tid] = 0;  // zero K-pad for decoder
}

// ---------- f32 -> bf16 conversion helpers ----------
__global__ void embed_kernel(const int* __restrict__ in1, const int* __restrict__ in2,
                             const float* __restrict__ emb, ushort_t* __restrict__ x0)
{
  int rowi = blockIdx.x;
  int l = threadIdx.x;    // 64 threads
  long r1 = (long)in1[rowi] * 400, r2 = (long)in2[rowi] * 400;
  ushort_t* d = x0 + (long)rowi * 800;
  for (int c = l; c < 800; c += 64)
    d[c] = f2b(c < 400 ? emb[r1 + c] : emb[r2 + c - 400]);
}

__global__ void pad_convert(const float* __restrict__ in, ushort_t* __restrict__ out,
                            int R, int Cin, int total, int Cp)
{
  int idx = blockIdx.x * 256 + threadIdx.x;
  if (idx >= total) return;
  int r = idx / Cp, c = idx - r * Cp;
  float v = (r < R && c < Cin) ? in[(long)r * Cin + c] : 0.f;
  out[idx] = f2b(v);
}

__global__ void init_state(const float* __restrict__ h_in,
                           ushort_t* __restrict__ hs, unsigned* __restrict__ flags)
{
  int idx = blockIdx.x * 256 + threadIdx.x;  // grid covers 64*1152 = 73728
  if (idx < 72 * 32) flags[idx] = 0u;        // reset barrier flag lines
  if (idx < 64 * 1152) {
    int b = idx / 1152, c = idx - b * 1152;
    hs[idx] = (c < 1150) ? f2b(h_in[b * 1150 + c]) : (ushort_t)0;
  }
  if (idx < 100 * 128) {  // zero K-pad cols of hs rows 1..100
    int t = idx >> 7, r = idx & 127, b = r >> 1, k = r & 1;
    hs[(long)(t + 1) * 73728 + b * 1152 + 1150 + k] = 0;
  }
}

// =====================================================================
extern "C" void kernel_launch(void* const* d_in, const int* in_sizes, int n_in,
                              void* d_out, int out_size, void* d_ws, size_t ws_size,
                              hipStream_t stream) {
  (void)in_sizes; (void)n_in; (void)out_size; (void)ws_size;
  const int* input  = (const int*)d_in[0];
  const int* input2 = (const int*)d_in[1];
  const float* h_in[3] = {(const float*)d_in[2], (const float*)d_in[4], (const float*)d_in[6]};
  const float* c_in[3] = {(const float*)d_in[3], (const float*)d_in[5], (const float*)d_in[7]};
  const float* emb_W = (const float*)d_in[8];
  const float* W_ih[3] = {(const float*)d_in[9],  (const float*)d_in[13], (const float*)d_in[17]};
  const float* W_hh[3] = {(const float*)d_in[10], (const float*)d_in[14], (const float*)d_in[18]};
  const float* b_ih[3] = {(const float*)d_in[11], (const float*)d_in[15], (const float*)d_in[19]};
  const float* b_hh[3] = {(const float*)d_in[12], (const float*)d_in[16], (const float*)d_in[20]};
  const float* dec_W = (const float*)d_in[21];
  const float* dec_b = (const float*)d_in[22];
  float* out = (float*)d_out;

  // allow 72KB dynamic LDS for the persistent LSTM kernel
  hipFuncSetAttribute((const void*)lstm_layer,
                      hipFuncAttributeMaxDynamicSharedMemorySize, 73728);

  // ---- workspace: buffers alive during the final decoder GEMM + flags ----
  char* base = (char*)d_ws;
  size_t off = 0;
  auto walloc = [&](size_t bytes) { char* r = base + off; off += (bytes + 255) & ~(size_t)255; return r; };
  ushort_t* decWp = (ushort_t*)walloc(33280ull * 1152 * 2);   // 76,677,120
  ushort_t* attnB = (ushort_t*)walloc(6400ull * 1152 * 2);    // 14,745,600
  unsigned* flags = (unsigned*)walloc(72 * 128 + 256);

  // ---- layer-phase scratch inside d_out (852 MB f32; scratch uses first
  //      ~120 MB, all dead before the decoder GEMM which reads only ws). ----
  char* ob = (char*)d_out;
  ushort_t* G   = (ushort_t*)(ob + 0);            // 58,982,400
  ushort_t* x0  = (ushort_t*)(ob + 58982400);     // 10,240,000
  ushort_t* Wp  = (ushort_t*)(ob + 69222400);     // 10,616,832
  ushort_t* Whp = (ushort_t*)(ob + 79839232);     // 10,616,832
  ushort_t* hsA = (ushort_t*)(ob + 90456064);     // 14,893,056
  ushort_t* hsB = (ushort_t*)(ob + 105349120);    // -> end 120,242,176

  embed_kernel<<<6400, 64, 0, stream>>>(input, input2, emb_W, x0);

  ushort_t* hcur[3] = {hsA, hsB, hsA};
  const ushort_t* X = x0;
  int lda = 800, Kp = 800;
  for (int lyr = 0; lyr < 3; lyr++) {
    if (lyr == 0) {
      int tot = 4608 * 800;
      pad_convert<<<(tot + 255) / 256, 256, 0, stream>>>(W_ih[0], Wp, 4600, 800, tot, 800);
    } else {
      int tot = 4608 * 1152;
      pad_convert<<<(tot + 255) / 256, 256, 0, stream>>>(W_ih[lyr], Wp, 4600, 1150, tot, 1152);
    }
    {
      int tot = 4608 * 1152;
      pad_convert<<<(tot + 255) / 256, 256, 0, stream>>>(W_hh[lyr], Whp, 4600, 1150, tot, 1152);
    }
    gemm_bt<false><<<dim3(50, 36), 256, 0, stream>>>(X, Wp, (void*)G, b_ih[lyr], b_hh[lyr],
                                                     lda, Kp, 4608, Kp, 4600);
    init_state<<<288, 256, 0, stream>>>(h_in[lyr], hcur[lyr], flags);
    lstm_layer<<<72, 256, 73728, stream>>>(hcur[lyr], G, Whp, c_in[lyr], flags);
    X = hcur[lyr] + 73728;
    lda = 1152; Kp = 1152;
  }

  attn_kernel<<<6400, 256, 0, stream>>>(hsA + 73728, attnB);

  {
    int tot = 33280 * 1152;
    pad_convert<<<(tot + 255) / 256, 256, 0, stream>>>(dec_W, decWp, 33278, 1150, tot, 1152);
  }

  gemm_bt<true><<<dim3(50, 260), 256, 0, stream>>>(attnB, decWp, (void*)out, dec_b, nullptr,
                                                   1152, 1152, 33278, 1152, 33278);
}